// Round 7
// baseline (180.457 us; speedup 1.0000x reference)
//
#include <hip/hip_runtime.h>

#define S_LEN 2048
#define E_DIM 1024
#define NH 16
#define DH 64

typedef __bf16 v8bf __attribute__((ext_vector_type(8)));
typedef float f32x4 __attribute__((ext_vector_type(4)));
typedef unsigned short u16x4 __attribute__((ext_vector_type(4)));
typedef unsigned short u16x8 __attribute__((ext_vector_type(8)));

// Static device scratch (fully rewritten each launch)
__device__ __align__(16) unsigned short g_Xb[S_LEN * E_DIM];       // x as bf16 [s][e]
__device__ __align__(16) unsigned short g_WT[3 * E_DIM * E_DIM];   // [3072][1024] K-major Wq|Wk|Wv (bf16)
__device__ __align__(16) unsigned short g_WoT[E_DIM * E_DIM];      // [1024][1024] Wo^T (K-major, bf16)
__device__ __align__(16) unsigned short g_Qb[NH * S_LEN * DH];     // [h][s][d]
__device__ __align__(16) unsigned short g_Kb[NH * S_LEN * DH];     // [h][t][d]
__device__ __align__(16) unsigned short g_Vt[NH * DH * S_LEN];     // [h][d][t]  (V transposed)
__device__ __align__(16) unsigned short g_AO[S_LEN * E_DIM];       // [s][h*64+d] (bf16)

__device__ inline unsigned short f2bf(float f) {
    unsigned int u = __float_as_uint(f);
    u += 0x7FFF + ((u >> 16) & 1);   // RNE
    return (unsigned short)(u >> 16);
}
__device__ inline f32x4 mfma16(v8bf a, v8bf b, f32x4 c) {
    return __builtin_amdgcn_mfma_f32_16x16x32_bf16(a, b, c, 0, 0, 0);
}
#define SWZ(v, pat) __int_as_float(__builtin_amdgcn_ds_swizzle(__float_as_int(v), (pat)))

// async global->LDS, 16B per lane; LDS dest = wave-uniform base + lane*16
typedef __attribute__((address_space(3))) unsigned int lds_u32;
typedef __attribute__((address_space(1))) const unsigned int glb_u32;
__device__ inline void async_cp16(const unsigned short* g, unsigned short* l) {
    __builtin_amdgcn_global_load_lds((glb_u32*)g, (lds_u32*)l, 16, 0, 0);
}

// ---------------- prep: convert x + transpose weights (vectorized) ----------------
__global__ __launch_bounds__(256) void prep(const float* __restrict__ X,
                                            const float* __restrict__ Wq,
                                            const float* __restrict__ Wk,
                                            const float* __restrict__ Wv,
                                            const float* __restrict__ Wo) {
    __shared__ __align__(16) unsigned short lds[64 * 72];
    const int b = blockIdx.x;
    const int t = threadIdx.x;
    if (b < 2048) {
        int i = b * 256 + t;
        f32x4 v = reinterpret_cast<const f32x4*>(X)[i];
        u16x4 o = {f2bf(v.x), f2bf(v.y), f2bf(v.z), f2bf(v.w)};
        reinterpret_cast<u16x4*>(g_Xb)[i] = o;
    } else if (b < 2304) {
        int bb = b - 2048;
        const int h = bb >> 4;
        const int e0 = (bb & 15) * 64;
        const float* srcs[3] = {Wq, Wk, Wv};
#pragma unroll
        for (int tn = 0; tn < 3; tn++) {
            const float* W = srcs[tn] + h * 65536;
#pragma unroll
            for (int p = 0; p < 4; p++) {
                int e = p * 16 + (t >> 4);
                int d = (t & 15) * 4;
                f32x4 v = *reinterpret_cast<const f32x4*>(&W[(e0 + e) * 64 + d]);
                lds[(d + 0) * 72 + e] = f2bf(v.x);
                lds[(d + 1) * 72 + e] = f2bf(v.y);
                lds[(d + 2) * 72 + e] = f2bf(v.z);
                lds[(d + 3) * 72 + e] = f2bf(v.w);
            }
            __syncthreads();
#pragma unroll
            for (int p = 0; p < 2; p++) {
                int d = p * 32 + (t >> 3);
                int ec = (t & 7) * 8;
                u16x8 o = *reinterpret_cast<const u16x8*>(&lds[d * 72 + ec]);
                *reinterpret_cast<u16x8*>(&g_WT[(tn * 1024 + h * 64 + d) * E_DIM + e0 + ec]) = o;
            }
            __syncthreads();
        }
    } else {
        int bb = b - 2304;
        const int f0 = (bb >> 4) * 64;
        const int e0 = (bb & 15) * 64;
#pragma unroll
        for (int p = 0; p < 4; p++) {
            int f = p * 16 + (t >> 4);
            int e = (t & 15) * 4;
            f32x4 v = *reinterpret_cast<const f32x4*>(&Wo[(f0 + f) * E_DIM + e0 + e]);
            lds[(e + 0) * 72 + f] = f2bf(v.x);
            lds[(e + 1) * 72 + f] = f2bf(v.y);
            lds[(e + 2) * 72 + f] = f2bf(v.z);
            lds[(e + 3) * 72 + f] = f2bf(v.w);
        }
        __syncthreads();
#pragma unroll
        for (int p = 0; p < 2; p++) {
            int e = p * 32 + (t >> 3);
            int fc = (t & 7) * 8;
            u16x8 o = *reinterpret_cast<const u16x8*>(&lds[e * 72 + fc]);
            *reinterpret_cast<u16x8*>(&g_WoT[(e0 + e) * E_DIM + f0 + fc]) = o;
        }
    }
}

// ---------------- QKV projection GEMM (128s x 64n, grid (16,48)) ----------------
// 4 waves; wave = 32s x 64n (2x4 accs); BK=64; one head per n-tile.
__global__ __launch_bounds__(256) void qkv_gemm(const float* __restrict__ bq,
                                                const float* __restrict__ bk,
                                                const float* __restrict__ bv) {
    __shared__ __align__(16) unsigned short lds[12288];   // 24KB: lA[0..8191] 128x64, lB[8192..] 64x64
    unsigned short* lA = lds;
    unsigned short* lB = lds + 8192;
    const int t = threadIdx.x;
    const int wave = t >> 6;
    const int lane = t & 63;
    const int m = lane & 15, quad = lane >> 4;
    const int s0 = blockIdx.x * 128;
    const int n0 = blockIdx.y * 64;

    const int rl = t >> 3;                       // 0..31
    const int cx = (t & 7) ^ (rl & 7);           // XOR chunk swizzle
    const int axor = m & 7;

    f32x4 acc[2][4];
#pragma unroll
    for (int i = 0; i < 2; i++)
#pragma unroll
        for (int j = 0; j < 4; j++) acc[i][j] = (f32x4){0.f, 0.f, 0.f, 0.f};

    const unsigned short* lAr0 = lA + (wave * 32 + m) * 64;
    const unsigned short* lAr1 = lA + (wave * 32 + 16 + m) * 64;

    for (int k0 = 0; k0 < E_DIM; k0 += 64) {
        const unsigned short* ga = g_Xb + (s0 + rl) * E_DIM + k0 + cx * 8;
        async_cp16(ga,              lA + wave * 512);
        async_cp16(ga + 32 * E_DIM, lA + 2048 + wave * 512);
        async_cp16(ga + 64 * E_DIM, lA + 4096 + wave * 512);
        async_cp16(ga + 96 * E_DIM, lA + 6144 + wave * 512);
        const unsigned short* gb = g_WT + (n0 + rl) * E_DIM + k0 + cx * 8;
        async_cp16(gb,              lB + wave * 512);
        async_cp16(gb + 32 * E_DIM, lB + 2048 + wave * 512);
        __syncthreads();
#pragma unroll
        for (int ks = 0; ks < 2; ks++) {
            const int ch = ((ks * 4 + quad) ^ axor) * 8;
            v8bf a0 = *reinterpret_cast<const v8bf*>(lAr0 + ch);
            v8bf a1 = *reinterpret_cast<const v8bf*>(lAr1 + ch);
#pragma unroll
            for (int j = 0; j < 4; j++) {
                v8bf bfr = *reinterpret_cast<const v8bf*>(lB + (j * 16 + m) * 64 + ch);
                acc[0][j] = mfma16(a0, bfr, acc[0][j]);
                acc[1][j] = mfma16(a1, bfr, acc[1][j]);
            }
        }
        __syncthreads();
    }

    const int tensor = n0 >> 10;                 // block-uniform
    const int nn0 = n0 & 1023;                   // = head*64
    const int hh = nn0 >> 6;
    const float* bb = tensor == 0 ? bq : (tensor == 1 ? bk : bv);
    float bias[4];
#pragma unroll
    for (int j = 0; j < 4; j++) bias[j] = bb[nn0 + j * 16 + m];

    if (tensor < 2) {
        // C -> LDS [sl][nl] stride 72 (128x72 = 18432 shorts fits in 24KB)
#pragma unroll
        for (int i = 0; i < 2; i++)
#pragma unroll
            for (int j = 0; j < 4; j++)
#pragma unroll
                for (int r = 0; r < 4; r++) {
                    int sl = wave * 32 + i * 16 + quad * 4 + r;
                    int nl = j * 16 + m;
                    lds[sl * 72 + nl] = f2bf(acc[i][j][r] + bias[j]);
                }
        __syncthreads();
        unsigned short* dst = (tensor == 0 ? g_Qb : g_Kb) + (hh * S_LEN + s0) * DH;
#pragma unroll
        for (int p = 0; p < 4; p++) {
            int row = p * 32 + (t >> 3);
            int c = t & 7;
            u16x8 v = *reinterpret_cast<const u16x8*>(&lds[row * 72 + c * 8]);
            *reinterpret_cast<u16x8*>(&dst[row * DH + c * 8]) = v;   // fully contiguous block
        }
    } else {
        // C -> LDS transposed [nl][sl] stride 136 (64x136 = 8704 shorts)
#pragma unroll
        for (int i = 0; i < 2; i++)
#pragma unroll
            for (int j = 0; j < 4; j++)
#pragma unroll
                for (int r = 0; r < 4; r++) {
                    int sl = wave * 32 + i * 16 + quad * 4 + r;
                    int nl = j * 16 + m;
                    lds[nl * 136 + sl] = f2bf(acc[i][j][r] + bias[j]);
                }
        __syncthreads();
#pragma unroll
        for (int p = 0; p < 4; p++) {
            int nl = p * 16 + (t >> 4);
            int sc = t & 15;
            u16x8 v = *reinterpret_cast<const u16x8*>(&lds[nl * 136 + sc * 8]);
            *reinterpret_cast<u16x8*>(&g_Vt[(hh * DH + nl) * S_LEN + s0 + sc * 8]) = v;
        }
    }
}

// ---------------- causal flash attention (balanced tile pairing + K-split) ----------------
// block = 4 waves; tiles A=[16j,16j+16), B=[2032-16j,2048-16j): combined work constant.
// wave w: k-tiles t0 = w*64 + 256k. Fixed-shift softmax => partials additive.
__global__ __launch_bounds__(256) void flash_attn() {
    __shared__ __align__(16) unsigned char smem[24576];
    unsigned short* plds = (unsigned short*)smem;        // per-wave 32x72 P region (18432 B)
    float* comb = (float*)smem;                          // [256][24] combine area (24576 B)
    const int t = threadIdx.x;
    const int wave = t >> 6, lane = t & 63;
    const int m = lane & 15, quad = lane >> 4;
    const int h = blockIdx.x & 15;
    const int j = blockIdx.x >> 4;                       // 0..63
    const int sA0 = j * 16;
    const int sB0 = 2032 - j * 16;

    const unsigned short* Qh = g_Qb + h * S_LEN * DH;
    const unsigned short* Kh = g_Kb + h * S_LEN * DH;
    const unsigned short* Vh = g_Vt + h * DH * S_LEN;

    v8bf aqA0 = *reinterpret_cast<const v8bf*>(Qh + (sA0 + m) * DH + quad * 8);
    v8bf aqA1 = *reinterpret_cast<const v8bf*>(Qh + (sA0 + m) * DH + 32 + quad * 8);
    v8bf aqB0 = *reinterpret_cast<const v8bf*>(Qh + (sB0 + m) * DH + quad * 8);
    v8bf aqB1 = *reinterpret_cast<const v8bf*>(Qh + (sB0 + m) * DH + 32 + quad * 8);

    f32x4 oA[4], oB[4];
#pragma unroll
    for (int i = 0; i < 4; i++) { oA[i] = (f32x4){0.f,0.f,0.f,0.f}; oB[i] = (f32x4){0.f,0.f,0.f,0.f}; }
    float lsA[4] = {0.f,0.f,0.f,0.f}, lsB[4] = {0.f,0.f,0.f,0.f};

    const float SC = 0.125f * 1.44269504088896f;         // 1/sqrt(64) * log2(e)
    unsigned short* pw = plds + wave * 2304;             // this wave's P region

    for (int t0 = wave * 64; t0 < sB0 + 16; t0 += 256) {
        const bool doA = (t0 < sA0 + 16);                // wave-uniform
        v8bf kf[4][2];
#pragma unroll
        for (int ct = 0; ct < 4; ct++) {
            const unsigned short* kp = Kh + (t0 + ct * 16 + m) * DH + quad * 8;
            kf[ct][0] = *reinterpret_cast<const v8bf*>(kp);
            kf[ct][1] = *reinterpret_cast<const v8bf*>(kp + 32);
        }
        f32x4 sB[4];
#pragma unroll
        for (int ct = 0; ct < 4; ct++) {
            sB[ct] = (f32x4){0.f,0.f,0.f,0.f};
            sB[ct] = mfma16(aqB0, kf[ct][0], sB[ct]);
            sB[ct] = mfma16(aqB1, kf[ct][1], sB[ct]);
        }
        f32x4 sA[4];
        if (doA) {
#pragma unroll
            for (int ct = 0; ct < 4; ct++) {
                sA[ct] = (f32x4){0.f,0.f,0.f,0.f};
                sA[ct] = mfma16(aqA0, kf[ct][0], sA[ct]);
                sA[ct] = mfma16(aqA1, kf[ct][1], sA[ct]);
            }
        }
        // causal masks
#pragma unroll
        for (int ct = 0; ct < 4; ct++) {
            int colbase = t0 + ct * 16;
            int col = colbase + m;
            if (colbase + 15 > sB0) {
#pragma unroll
                for (int r = 0; r < 4; r++)
                    if (col > sB0 + quad * 4 + r) sB[ct][r] = -3e38f;
            }
            if (doA && colbase + 15 > sA0) {
#pragma unroll
                for (int r = 0; r < 4; r++)
                    if (col > sA0 + quad * 4 + r) sA[ct][r] = -3e38f;
            }
        }
        v8bf vf[4][2];
#pragma unroll
        for (int dt = 0; dt < 4; dt++) {
            const unsigned short* vp = Vh + (dt * 16 + m) * S_LEN + t0 + quad * 8;
            vf[dt][0] = *reinterpret_cast<const v8bf*>(vp);
            vf[dt][1] = *reinterpret_cast<const v8bf*>(vp + 32);
        }
#pragma unroll
        for (int ct = 0; ct < 4; ct++)
#pragma unroll
            for (int r = 0; r < 4; r++)
                sB[ct][r] = __builtin_amdgcn_exp2f(sB[ct][r] * SC);
#pragma unroll
        for (int r = 0; r < 4; r++)
            lsB[r] += (sB[0][r] + sB[1][r]) + (sB[2][r] + sB[3][r]);
#pragma unroll
        for (int ct = 0; ct < 4; ct++)
#pragma unroll
            for (int r = 0; r < 4; r++)
                pw[(16 + quad * 4 + r) * 72 + ct * 16 + m] = f2bf(sB[ct][r]);
        if (doA) {
#pragma unroll
            for (int ct = 0; ct < 4; ct++)
#pragma unroll
                for (int r = 0; r < 4; r++)
                    sA[ct][r] = __builtin_amdgcn_exp2f(sA[ct][r] * SC);
#pragma unroll
            for (int r = 0; r < 4; r++)
                lsA[r] += (sA[0][r] + sA[1][r]) + (sA[2][r] + sA[3][r]);
#pragma unroll
            for (int ct = 0; ct < 4; ct++)
#pragma unroll
                for (int r = 0; r < 4; r++)
                    pw[(quad * 4 + r) * 72 + ct * 16 + m] = f2bf(sA[ct][r]);
        }
        __builtin_amdgcn_s_waitcnt(0xC07F);              // lgkmcnt(0): same-wave LDS roundtrip
        v8bf apB0 = *reinterpret_cast<const v8bf*>(pw + (16 + m) * 72 + quad * 8);
        v8bf apB1 = *reinterpret_cast<const v8bf*>(pw + (16 + m) * 72 + 32 + quad * 8);
#pragma unroll
        for (int dt = 0; dt < 4; dt++) {
            oB[dt] = mfma16(apB0, vf[dt][0], oB[dt]);
            oB[dt] = mfma16(apB1, vf[dt][1], oB[dt]);
        }
        if (doA) {
            v8bf apA0 = *reinterpret_cast<const v8bf*>(pw + m * 72 + quad * 8);
            v8bf apA1 = *reinterpret_cast<const v8bf*>(pw + m * 72 + 32 + quad * 8);
#pragma unroll
            for (int dt = 0; dt < 4; dt++) {
                oA[dt] = mfma16(apA0, vf[dt][0], oA[dt]);
                oA[dt] = mfma16(apA1, vf[dt][1], oA[dt]);
            }
        }
    }

    // ---- 2-phase cross-wave combine (o,l additive) ----
    float* cw = comb + (wave * 64 + lane) * 24;
    __syncthreads();                                     // P regions dead
#pragma unroll
    for (int dt = 0; dt < 4; dt++) *reinterpret_cast<f32x4*>(cw + dt * 4) = oA[dt];
    *reinterpret_cast<f32x4*>(cw + 16) = (f32x4){lsA[0], lsA[1], lsA[2], lsA[3]};
    __syncthreads();
    {
        f32x4 oAt = (f32x4){0.f,0.f,0.f,0.f}, l4 = (f32x4){0.f,0.f,0.f,0.f};
#pragma unroll
        for (int w = 0; w < 4; w++) {
            const float* cr = comb + (w * 64 + lane) * 24;
            oAt += *reinterpret_cast<const f32x4*>(cr + wave * 4);
            l4  += *reinterpret_cast<const f32x4*>(cr + 16);
        }
#pragma unroll
        for (int r = 0; r < 4; r++) {
            float a = l4[r];
            a += SWZ(a, 0x041F); a += SWZ(a, 0x081F);
            a += SWZ(a, 0x101F); a += SWZ(a, 0x201F);
            float inv = 1.0f / a;
            g_AO[(sA0 + quad * 4 + r) * E_DIM + h * 64 + wave * 16 + m] = f2bf(oAt[r] * inv);
        }
    }
    __syncthreads();
#pragma unroll
    for (int dt = 0; dt < 4; dt++) *reinterpret_cast<f32x4*>(cw + dt * 4) = oB[dt];
    *reinterpret_cast<f32x4*>(cw + 16) = (f32x4){lsB[0], lsB[1], lsB[2], lsB[3]};
    __syncthreads();
    {
        f32x4 oBt = (f32x4){0.f,0.f,0.f,0.f}, l4 = (f32x4){0.f,0.f,0.f,0.f};
#pragma unroll
        for (int w = 0; w < 4; w++) {
            const float* cr = comb + (w * 64 + lane) * 24;
            oBt += *reinterpret_cast<const f32x4*>(cr + wave * 4);
            l4  += *reinterpret_cast<const f32x4*>(cr + 16);
        }
#pragma unroll
        for (int r = 0; r < 4; r++) {
            float a = l4[r];
            a += SWZ(a, 0x041F); a += SWZ(a, 0x081F);
            a += SWZ(a, 0x101F); a += SWZ(a, 0x201F);
            float inv = 1.0f / a;
            g_AO[(sB0 + quad * 4 + r) * E_DIM + h * 64 + wave * 16 + m] = f2bf(oBt[r] * inv);
        }
    }
}

// ---------------- output projection (64s x 64n, grid (32,16)) ----------------
__global__ __launch_bounds__(256) void out_gemm(const float* __restrict__ bo,
                                                float* __restrict__ OUT) {
    __shared__ __align__(16) unsigned short lds[8192];   // lA 64x64, lB 64x64
    unsigned short* lA = lds;
    unsigned short* lB = lds + 4096;
    const int t = threadIdx.x;
    const int wave = t >> 6;
    const int lane = t & 63;
    const int m = lane & 15, quad = lane >> 4;
    const int wr = (wave >> 1) * 32, wc = (wave & 1) * 32;
    const int s0 = blockIdx.x * 64;
    const int n0 = blockIdx.y * 64;

    const int rl = t >> 3;
    const int cx = (t & 7) ^ (rl & 7);
    const int axor = m & 7;

    f32x4 acc[2][2];
#pragma unroll
    for (int i = 0; i < 2; i++)
#pragma unroll
        for (int j = 0; j < 2; j++) acc[i][j] = (f32x4){0.f, 0.f, 0.f, 0.f};

    for (int k0 = 0; k0 < E_DIM; k0 += 64) {
        const unsigned short* ga = g_AO + (s0 + rl) * E_DIM + k0 + cx * 8;
        async_cp16(ga,              lA + wave * 512);
        async_cp16(ga + 32 * E_DIM, lA + 2048 + wave * 512);
        const unsigned short* gb = g_WoT + (n0 + rl) * E_DIM + k0 + cx * 8;
        async_cp16(gb,              lB + wave * 512);
        async_cp16(gb + 32 * E_DIM, lB + 2048 + wave * 512);
        __syncthreads();
#pragma unroll
        for (int ks = 0; ks < 2; ks++) {
            const int ch = ((ks * 4 + quad) ^ axor) * 8;
            v8bf a0 = *reinterpret_cast<const v8bf*>(lA + (wr + m) * 64 + ch);
            v8bf a1 = *reinterpret_cast<const v8bf*>(lA + (wr + 16 + m) * 64 + ch);
#pragma unroll
            for (int j = 0; j < 2; j++) {
                v8bf bfr = *reinterpret_cast<const v8bf*>(lB + (wc + j * 16 + m) * 64 + ch);
                acc[0][j] = mfma16(a0, bfr, acc[0][j]);
                acc[1][j] = mfma16(a1, bfr, acc[1][j]);
            }
        }
        __syncthreads();
    }
#pragma unroll
    for (int i = 0; i < 2; i++)
#pragma unroll
        for (int j = 0; j < 2; j++) {
            int e = n0 + wc + j * 16 + m;
            float bias = bo[e];
#pragma unroll
            for (int r = 0; r < 4; r++) {
                int s = s0 + wr + i * 16 + quad * 4 + r;
                OUT[s * E_DIM + e] = acc[i][j][r] + bias;
            }
        }
}

extern "C" void kernel_launch(void* const* d_in, const int* in_sizes, int n_in,
                              void* d_out, int out_size, void* d_ws, size_t ws_size,
                              hipStream_t stream) {
    (void)in_sizes; (void)n_in; (void)out_size; (void)d_ws; (void)ws_size;
    const float* x  = (const float*)d_in[0];
    const float* Wq = (const float*)d_in[1];
    const float* bq = (const float*)d_in[2];
    const float* Wk = (const float*)d_in[3];
    const float* bk = (const float*)d_in[4];
    const float* Wv = (const float*)d_in[5];
    const float* bv = (const float*)d_in[6];
    const float* Wo = (const float*)d_in[7];
    const float* bo = (const float*)d_in[8];
    float* out = (float*)d_out;

    hipLaunchKernelGGL(prep,       dim3(2560),   dim3(256), 0, stream, x, Wq, Wk, Wv, Wo);
    hipLaunchKernelGGL(qkv_gemm,   dim3(16, 48), dim3(256), 0, stream, bq, bk, bv);
    hipLaunchKernelGGL(flash_attn, dim3(1024),   dim3(256), 0, stream);
    hipLaunchKernelGGL(out_gemm,   dim3(32, 16), dim3(256), 0, stream, bo, out);
}

// Round 8
// 167.531 us; speedup vs baseline: 1.0772x; 1.0772x over previous
//
#include <hip/hip_runtime.h>
#include <hip/hip_bf16.h>

#define S_LEN 2048
#define E_DIM 1024
#define NH 16
#define DH 64

typedef __bf16 v8bf __attribute__((ext_vector_type(8)));
typedef float f32x4 __attribute__((ext_vector_type(4)));
typedef unsigned short u16x4 __attribute__((ext_vector_type(4)));
typedef unsigned short u16x8 __attribute__((ext_vector_type(8)));

// Static device scratch (fully rewritten each launch)
__device__ __align__(16) unsigned short g_Xb[S_LEN * E_DIM];       // x as bf16 [s][e]
__device__ __align__(16) unsigned short g_WT[3 * E_DIM * E_DIM];   // [3072][1024] K-major Wq|Wk|Wv (bf16)
__device__ __align__(16) unsigned short g_WoT[E_DIM * E_DIM];      // [1024][1024] Wo^T (K-major, bf16)
__device__ __align__(16) unsigned short g_Qb[NH * S_LEN * DH];     // [h][s][d]
__device__ __align__(16) unsigned short g_Kb[NH * S_LEN * DH];     // [h][t][d]
__device__ __align__(16) unsigned short g_Vt[NH * DH * S_LEN];     // [h][d][t]  (V transposed)
__device__ __align__(16) unsigned short g_AO[S_LEN * E_DIM];       // [s][h*64+d] (bf16)

__device__ inline unsigned short f2bf(float f) {
    unsigned int u = __float_as_uint(f);
    u += 0x7FFF + ((u >> 16) & 1);   // RNE
    return (unsigned short)(u >> 16);
}
__device__ inline f32x4 mfma16(v8bf a, v8bf b, f32x4 c) {
    return __builtin_amdgcn_mfma_f32_16x16x32_bf16(a, b, c, 0, 0, 0);
}

// async global->LDS, 16B per lane; LDS dest = wave-uniform base + lane*16
typedef __attribute__((address_space(3))) unsigned int lds_u32;
typedef __attribute__((address_space(1))) const unsigned int glb_u32;
__device__ inline void async_cp16(const unsigned short* g, unsigned short* l) {
    __builtin_amdgcn_global_load_lds((glb_u32*)g, (lds_u32*)l, 16, 0, 0);
}

// ---------------- prep: convert x + transpose weights (vectorized) ----------------
__global__ __launch_bounds__(256) void prep(const float* __restrict__ X,
                                            const float* __restrict__ Wq,
                                            const float* __restrict__ Wk,
                                            const float* __restrict__ Wv,
                                            const float* __restrict__ Wo) {
    __shared__ __align__(16) unsigned short lds[64 * 72];
    const int b = blockIdx.x;
    const int t = threadIdx.x;
    if (b < 2048) {
        int i = b * 256 + t;
        f32x4 v = reinterpret_cast<const f32x4*>(X)[i];
        u16x4 o = {f2bf(v.x), f2bf(v.y), f2bf(v.z), f2bf(v.w)};
        reinterpret_cast<u16x4*>(g_Xb)[i] = o;
    } else if (b < 2304) {
        int bb = b - 2048;
        const int h = bb >> 4;
        const int e0 = (bb & 15) * 64;
        const float* srcs[3] = {Wq, Wk, Wv};
#pragma unroll
        for (int tn = 0; tn < 3; tn++) {
            const float* W = srcs[tn] + h * 65536;
#pragma unroll
            for (int p = 0; p < 4; p++) {
                int e = p * 16 + (t >> 4);
                int d = (t & 15) * 4;
                f32x4 v = *reinterpret_cast<const f32x4*>(&W[(e0 + e) * 64 + d]);
                lds[(d + 0) * 72 + e] = f2bf(v.x);
                lds[(d + 1) * 72 + e] = f2bf(v.y);
                lds[(d + 2) * 72 + e] = f2bf(v.z);
                lds[(d + 3) * 72 + e] = f2bf(v.w);
            }
            __syncthreads();
#pragma unroll
            for (int p = 0; p < 2; p++) {
                int d = p * 32 + (t >> 3);
                int ec = (t & 7) * 8;
                u16x8 o = *reinterpret_cast<const u16x8*>(&lds[d * 72 + ec]);
                *reinterpret_cast<u16x8*>(&g_WT[(tn * 1024 + h * 64 + d) * E_DIM + e0 + ec]) = o;
            }
            __syncthreads();
        }
    } else {
        int bb = b - 2304;
        const int f0 = (bb >> 4) * 64;
        const int e0 = (bb & 15) * 64;
#pragma unroll
        for (int p = 0; p < 4; p++) {
            int f = p * 16 + (t >> 4);
            int e = (t & 15) * 4;
            f32x4 v = *reinterpret_cast<const f32x4*>(&Wo[(f0 + f) * E_DIM + e0 + e]);
            lds[(e + 0) * 72 + f] = f2bf(v.x);
            lds[(e + 1) * 72 + f] = f2bf(v.y);
            lds[(e + 2) * 72 + f] = f2bf(v.z);
            lds[(e + 3) * 72 + f] = f2bf(v.w);
        }
        __syncthreads();
#pragma unroll
        for (int p = 0; p < 2; p++) {
            int e = p * 32 + (t >> 3);
            int fc = (t & 7) * 8;
            u16x8 o = *reinterpret_cast<const u16x8*>(&lds[e * 72 + fc]);
            *reinterpret_cast<u16x8*>(&g_WoT[(e0 + e) * E_DIM + f0 + fc]) = o;
        }
    }
}

// ---------------- QKV projection GEMM (128s x 64n, grid (16,48)) ----------------
__global__ __launch_bounds__(256) void qkv_gemm(const float* __restrict__ bq,
                                                const float* __restrict__ bk,
                                                const float* __restrict__ bv) {
    __shared__ __align__(16) unsigned short lds[12288];   // 24KB: lA 128x64, lB 64x64
    unsigned short* lA = lds;
    unsigned short* lB = lds + 8192;
    const int t = threadIdx.x;
    const int wave = t >> 6;
    const int lane = t & 63;
    const int m = lane & 15, quad = lane >> 4;
    const int s0 = blockIdx.x * 128;
    const int n0 = blockIdx.y * 64;

    const int rl = t >> 3;
    const int cx = (t & 7) ^ (rl & 7);
    const int axor = m & 7;

    f32x4 acc[2][4];
#pragma unroll
    for (int i = 0; i < 2; i++)
#pragma unroll
        for (int j = 0; j < 4; j++) acc[i][j] = (f32x4){0.f, 0.f, 0.f, 0.f};

    const unsigned short* lAr0 = lA + (wave * 32 + m) * 64;
    const unsigned short* lAr1 = lA + (wave * 32 + 16 + m) * 64;

    for (int k0 = 0; k0 < E_DIM; k0 += 64) {
        const unsigned short* ga = g_Xb + (s0 + rl) * E_DIM + k0 + cx * 8;
        async_cp16(ga,              lA + wave * 512);
        async_cp16(ga + 32 * E_DIM, lA + 2048 + wave * 512);
        async_cp16(ga + 64 * E_DIM, lA + 4096 + wave * 512);
        async_cp16(ga + 96 * E_DIM, lA + 6144 + wave * 512);
        const unsigned short* gb = g_WT + (n0 + rl) * E_DIM + k0 + cx * 8;
        async_cp16(gb,              lB + wave * 512);
        async_cp16(gb + 32 * E_DIM, lB + 2048 + wave * 512);
        __syncthreads();
#pragma unroll
        for (int ks = 0; ks < 2; ks++) {
            const int ch = ((ks * 4 + quad) ^ axor) * 8;
            v8bf a0 = *reinterpret_cast<const v8bf*>(lAr0 + ch);
            v8bf a1 = *reinterpret_cast<const v8bf*>(lAr1 + ch);
#pragma unroll
            for (int j = 0; j < 4; j++) {
                v8bf bfr = *reinterpret_cast<const v8bf*>(lB + (j * 16 + m) * 64 + ch);
                acc[0][j] = mfma16(a0, bfr, acc[0][j]);
                acc[1][j] = mfma16(a1, bfr, acc[1][j]);
            }
        }
        __syncthreads();
    }

    const int tensor = n0 >> 10;
    const int nn0 = n0 & 1023;
    const int hh = nn0 >> 6;
    const float* bb = tensor == 0 ? bq : (tensor == 1 ? bk : bv);
    float bias[4];
#pragma unroll
    for (int j = 0; j < 4; j++) bias[j] = bb[nn0 + j * 16 + m];

    if (tensor < 2) {
#pragma unroll
        for (int i = 0; i < 2; i++)
#pragma unroll
            for (int j = 0; j < 4; j++)
#pragma unroll
                for (int r = 0; r < 4; r++) {
                    int sl = wave * 32 + i * 16 + quad * 4 + r;
                    int nl = j * 16 + m;
                    lds[sl * 72 + nl] = f2bf(acc[i][j][r] + bias[j]);
                }
        __syncthreads();
        unsigned short* dst = (tensor == 0 ? g_Qb : g_Kb) + (hh * S_LEN + s0) * DH;
#pragma unroll
        for (int p = 0; p < 4; p++) {
            int row = p * 32 + (t >> 3);
            int c = t & 7;
            u16x8 v = *reinterpret_cast<const u16x8*>(&lds[row * 72 + c * 8]);
            *reinterpret_cast<u16x8*>(&dst[row * DH + c * 8]) = v;
        }
    } else {
#pragma unroll
        for (int i = 0; i < 2; i++)
#pragma unroll
            for (int j = 0; j < 4; j++)
#pragma unroll
                for (int r = 0; r < 4; r++) {
                    int sl = wave * 32 + i * 16 + quad * 4 + r;
                    int nl = j * 16 + m;
                    lds[nl * 136 + sl] = f2bf(acc[i][j][r] + bias[j]);
                }
        __syncthreads();
#pragma unroll
        for (int p = 0; p < 4; p++) {
            int nl = p * 16 + (t >> 4);
            int sc = t & 15;
            u16x8 v = *reinterpret_cast<const u16x8*>(&lds[nl * 136 + sc * 8]);
            *reinterpret_cast<u16x8*>(&g_Vt[(hh * DH + nl) * S_LEN + s0 + sc * 8]) = v;
        }
    }
}

// ---------------- causal flash attention ----------------
// R6 structure: contiguous 32-row q-tile per block, 4-wave K-split (t0=wave*64, +=256).
// CU-balanced tile map: round-robin dispatch gives CU c tiles {T0,T0+16,T0+32,T0+48};
// bijection {t, 31-t, 32+t, 63-t} makes every CU's 4-tile work sum constant.
// l computed via ones-vector MFMA (C-layout, rows aligned with O) — no swizzle reduces.
__global__ __launch_bounds__(256) void flash_attn() {
    __shared__ __align__(16) unsigned char smem[24576];
    unsigned short* plds = (unsigned short*)smem;        // per-wave 32x72 P region
    float* comb = (float*)smem;                          // [256][24] combine area
    const int t = threadIdx.x;
    const int wave = t >> 6, lane = t & 63;
    const int m = lane & 15, quad = lane >> 4;
    const int h = blockIdx.x & 15;
    const int Tp = blockIdx.x >> 4;                      // 0..63
    const int qq = Tp >> 4, tt = Tp & 15;
    const int T = (qq == 0) ? tt : (qq == 1) ? 31 - tt : (qq == 2) ? 32 + tt : 63 - tt;
    const int s0 = T * 32;

    const unsigned short* Qh = g_Qb + h * S_LEN * DH;
    const unsigned short* Kh = g_Kb + h * S_LEN * DH;
    const unsigned short* Vh = g_Vt + h * DH * S_LEN;

    v8bf aqA0 = *reinterpret_cast<const v8bf*>(Qh + (s0 + m) * DH + quad * 8);
    v8bf aqA1 = *reinterpret_cast<const v8bf*>(Qh + (s0 + m) * DH + 32 + quad * 8);
    v8bf aqB0 = *reinterpret_cast<const v8bf*>(Qh + (s0 + 16 + m) * DH + quad * 8);
    v8bf aqB1 = *reinterpret_cast<const v8bf*>(Qh + (s0 + 16 + m) * DH + 32 + quad * 8);

    f32x4 oA[4], oB[4];
#pragma unroll
    for (int i = 0; i < 4; i++) { oA[i] = (f32x4){0.f,0.f,0.f,0.f}; oB[i] = (f32x4){0.f,0.f,0.f,0.f}; }
    f32x4 laccA = (f32x4){0.f,0.f,0.f,0.f}, laccB = (f32x4){0.f,0.f,0.f,0.f};

    v8bf ones;
#pragma unroll
    for (int i = 0; i < 8; i++) ones[i] = (__bf16)1.0f;

    const float SC = 0.125f * 1.44269504088896f;         // 1/sqrt(64) * log2(e)
    unsigned short* pw = plds + wave * 2304;             // this wave's P region (32x72)

    for (int t0 = wave * 64; t0 < s0 + 32; t0 += 256) {
        const bool doA = (t0 < s0 + 16);                 // wave-uniform
        v8bf kf[4][2];
#pragma unroll
        for (int ct = 0; ct < 4; ct++) {
            const unsigned short* kp = Kh + (t0 + ct * 16 + m) * DH + quad * 8;
            kf[ct][0] = *reinterpret_cast<const v8bf*>(kp);
            kf[ct][1] = *reinterpret_cast<const v8bf*>(kp + 32);
        }
        f32x4 sB[4];
#pragma unroll
        for (int ct = 0; ct < 4; ct++) {
            sB[ct] = (f32x4){0.f,0.f,0.f,0.f};
            sB[ct] = mfma16(aqB0, kf[ct][0], sB[ct]);
            sB[ct] = mfma16(aqB1, kf[ct][1], sB[ct]);
        }
        f32x4 sA[4];
        if (doA) {
#pragma unroll
            for (int ct = 0; ct < 4; ct++) {
                sA[ct] = (f32x4){0.f,0.f,0.f,0.f};
                sA[ct] = mfma16(aqA0, kf[ct][0], sA[ct]);
                sA[ct] = mfma16(aqA1, kf[ct][1], sA[ct]);
            }
        }
        // causal masks (tile A rows s0.., tile B rows s0+16..)
#pragma unroll
        for (int ct = 0; ct < 4; ct++) {
            int colbase = t0 + ct * 16;
            int col = colbase + m;
            if (colbase + 15 > s0 + 16) {
#pragma unroll
                for (int r = 0; r < 4; r++)
                    if (col > s0 + 16 + quad * 4 + r) sB[ct][r] = -3e38f;
            }
            if (doA && colbase + 15 > s0) {
#pragma unroll
                for (int r = 0; r < 4; r++)
                    if (col > s0 + quad * 4 + r) sA[ct][r] = -3e38f;
            }
        }
        v8bf vf[4][2];
#pragma unroll
        for (int dt = 0; dt < 4; dt++) {
            const unsigned short* vp = Vh + (dt * 16 + m) * S_LEN + t0 + quad * 8;
            vf[dt][0] = *reinterpret_cast<const v8bf*>(vp);
            vf[dt][1] = *reinterpret_cast<const v8bf*>(vp + 32);
        }
        // p = exp2(s*SC); packed bf16 convert (v_cvt_pk_bf16_f32); P -> LDS
#pragma unroll
        for (int ct = 0; ct < 4; ct++) {
#pragma unroll
            for (int r = 0; r < 4; r++)
                sB[ct][r] = __builtin_amdgcn_exp2f(sB[ct][r] * SC);
            __hip_bfloat162 p01 = __float22bfloat162_rn(make_float2(sB[ct][0], sB[ct][1]));
            __hip_bfloat162 p23 = __float22bfloat162_rn(make_float2(sB[ct][2], sB[ct][3]));
            unsigned short* pb = pw + (16 + quad * 4) * 72 + ct * 16 + m;
            pb[0]       = *reinterpret_cast<unsigned short*>(&p01.x);
            pb[72]      = *reinterpret_cast<unsigned short*>(&p01.y);
            pb[144]     = *reinterpret_cast<unsigned short*>(&p23.x);
            pb[216]     = *reinterpret_cast<unsigned short*>(&p23.y);
        }
        if (doA) {
#pragma unroll
            for (int ct = 0; ct < 4; ct++) {
#pragma unroll
                for (int r = 0; r < 4; r++)
                    sA[ct][r] = __builtin_amdgcn_exp2f(sA[ct][r] * SC);
                __hip_bfloat162 p01 = __float22bfloat162_rn(make_float2(sA[ct][0], sA[ct][1]));
                __hip_bfloat162 p23 = __float22bfloat162_rn(make_float2(sA[ct][2], sA[ct][3]));
                unsigned short* pa = pw + (quad * 4) * 72 + ct * 16 + m;
                pa[0]   = *reinterpret_cast<unsigned short*>(&p01.x);
                pa[72]  = *reinterpret_cast<unsigned short*>(&p01.y);
                pa[144] = *reinterpret_cast<unsigned short*>(&p23.x);
                pa[216] = *reinterpret_cast<unsigned short*>(&p23.y);
            }
        }
        __builtin_amdgcn_s_waitcnt(0xC07F);              // lgkmcnt(0): same-wave LDS roundtrip
        v8bf apB0 = *reinterpret_cast<const v8bf*>(pw + (16 + m) * 72 + quad * 8);
        v8bf apB1 = *reinterpret_cast<const v8bf*>(pw + (16 + m) * 72 + 32 + quad * 8);
#pragma unroll
        for (int dt = 0; dt < 4; dt++) {
            oB[dt] = mfma16(apB0, vf[dt][0], oB[dt]);
            oB[dt] = mfma16(apB1, vf[dt][1], oB[dt]);
        }
        laccB = mfma16(apB0, ones, laccB);               // l partial: rows match O's C-layout
        laccB = mfma16(apB1, ones, laccB);
        if (doA) {
            v8bf apA0 = *reinterpret_cast<const v8bf*>(pw + m * 72 + quad * 8);
            v8bf apA1 = *reinterpret_cast<const v8bf*>(pw + m * 72 + 32 + quad * 8);
#pragma unroll
            for (int dt = 0; dt < 4; dt++) {
                oA[dt] = mfma16(apA0, vf[dt][0], oA[dt]);
                oA[dt] = mfma16(apA1, vf[dt][1], oA[dt]);
            }
            laccA = mfma16(apA0, ones, laccA);
            laccA = mfma16(apA1, ones, laccA);
        }
    }

    // ---- 2-phase cross-wave combine (o,l additive; l already per-row, no lane reduce) ----
    float* cw = comb + (wave * 64 + lane) * 24;
    __syncthreads();                                     // P regions dead
#pragma unroll
    for (int dt = 0; dt < 4; dt++) *reinterpret_cast<f32x4*>(cw + dt * 4) = oA[dt];
    *reinterpret_cast<f32x4*>(cw + 16) = laccA;
    __syncthreads();
    {
        f32x4 oAt = (f32x4){0.f,0.f,0.f,0.f}, l4 = (f32x4){0.f,0.f,0.f,0.f};
#pragma unroll
        for (int w = 0; w < 4; w++) {
            const float* cr = comb + (w * 64 + lane) * 24;
            oAt += *reinterpret_cast<const f32x4*>(cr + wave * 4);
            l4  += *reinterpret_cast<const f32x4*>(cr + 16);
        }
#pragma unroll
        for (int r = 0; r < 4; r++) {
            float inv = 1.0f / l4[r];
            g_AO[(s0 + quad * 4 + r) * E_DIM + h * 64 + wave * 16 + m] = f2bf(oAt[r] * inv);
        }
    }
    __syncthreads();
#pragma unroll
    for (int dt = 0; dt < 4; dt++) *reinterpret_cast<f32x4*>(cw + dt * 4) = oB[dt];
    *reinterpret_cast<f32x4*>(cw + 16) = laccB;
    __syncthreads();
    {
        f32x4 oBt = (f32x4){0.f,0.f,0.f,0.f}, l4 = (f32x4){0.f,0.f,0.f,0.f};
#pragma unroll
        for (int w = 0; w < 4; w++) {
            const float* cr = comb + (w * 64 + lane) * 24;
            oBt += *reinterpret_cast<const f32x4*>(cr + wave * 4);
            l4  += *reinterpret_cast<const f32x4*>(cr + 16);
        }
#pragma unroll
        for (int r = 0; r < 4; r++) {
            float inv = 1.0f / l4[r];
            g_AO[(s0 + 16 + quad * 4 + r) * E_DIM + h * 64 + wave * 16 + m] = f2bf(oBt[r] * inv);
        }
    }
}

// ---------------- output projection (64s x 64n, grid (32,16)) ----------------
__global__ __launch_bounds__(256) void out_gemm(const float* __restrict__ bo,
                                                float* __restrict__ OUT) {
    __shared__ __align__(16) unsigned short lds[8192];
    unsigned short* lA = lds;
    unsigned short* lB = lds + 4096;
    const int t = threadIdx.x;
    const int wave = t >> 6;
    const int lane = t & 63;
    const int m = lane & 15, quad = lane >> 4;
    const int wr = (wave >> 1) * 32, wc = (wave & 1) * 32;
    const int s0 = blockIdx.x * 64;
    const int n0 = blockIdx.y * 64;

    const int rl = t >> 3;
    const int cx = (t & 7) ^ (rl & 7);
    const int axor = m & 7;

    f32x4 acc[2][2];
#pragma unroll
    for (int i = 0; i < 2; i++)
#pragma unroll
        for (int j = 0; j < 2; j++) acc[i][j] = (f32x4){0.f, 0.f, 0.f, 0.f};

    for (int k0 = 0; k0 < E_DIM; k0 += 64) {
        const unsigned short* ga = g_AO + (s0 + rl) * E_DIM + k0 + cx * 8;
        async_cp16(ga,              lA + wave * 512);
        async_cp16(ga + 32 * E_DIM, lA + 2048 + wave * 512);
        const unsigned short* gb = g_WoT + (n0 + rl) * E_DIM + k0 + cx * 8;
        async_cp16(gb,              lB + wave * 512);
        async_cp16(gb + 32 * E_DIM, lB + 2048 + wave * 512);
        __syncthreads();
#pragma unroll
        for (int ks = 0; ks < 2; ks++) {
            const int ch = ((ks * 4 + quad) ^ axor) * 8;
            v8bf a0 = *reinterpret_cast<const v8bf*>(lA + (wr + m) * 64 + ch);
            v8bf a1 = *reinterpret_cast<const v8bf*>(lA + (wr + 16 + m) * 64 + ch);
#pragma unroll
            for (int j = 0; j < 2; j++) {
                v8bf bfr = *reinterpret_cast<const v8bf*>(lB + (wc + j * 16 + m) * 64 + ch);
                acc[0][j] = mfma16(a0, bfr, acc[0][j]);
                acc[1][j] = mfma16(a1, bfr, acc[1][j]);
            }
        }
        __syncthreads();
    }
#pragma unroll
    for (int i = 0; i < 2; i++)
#pragma unroll
        for (int j = 0; j < 2; j++) {
            int e = n0 + wc + j * 16 + m;
            float bias = bo[e];
#pragma unroll
            for (int r = 0; r < 4; r++) {
                int s = s0 + wr + i * 16 + quad * 4 + r;
                OUT[s * E_DIM + e] = acc[i][j][r] + bias;
            }
        }
}

extern "C" void kernel_launch(void* const* d_in, const int* in_sizes, int n_in,
                              void* d_out, int out_size, void* d_ws, size_t ws_size,
                              hipStream_t stream) {
    (void)in_sizes; (void)n_in; (void)out_size; (void)d_ws; (void)ws_size;
    const float* x  = (const float*)d_in[0];
    const float* Wq = (const float*)d_in[1];
    const float* bq = (const float*)d_in[2];
    const float* Wk = (const float*)d_in[3];
    const float* bk = (const float*)d_in[4];
    const float* Wv = (const float*)d_in[5];
    const float* bv = (const float*)d_in[6];
    const float* Wo = (const float*)d_in[7];
    const float* bo = (const float*)d_in[8];
    float* out = (float*)d_out;

    hipLaunchKernelGGL(prep,       dim3(2560),   dim3(256), 0, stream, x, Wq, Wk, Wv, Wo);
    hipLaunchKernelGGL(qkv_gemm,   dim3(16, 48), dim3(256), 0, stream, bq, bk, bv);
    hipLaunchKernelGGL(flash_attn, dim3(1024),   dim3(256), 0, stream);
    hipLaunchKernelGGL(out_gemm,   dim3(32, 16), dim3(256), 0, stream, bo, out);
}

// Round 9
// 166.592 us; speedup vs baseline: 1.0832x; 1.0056x over previous
//
#include <hip/hip_runtime.h>
#include <hip/hip_bf16.h>

#define S_LEN 2048
#define E_DIM 1024
#define NH 16
#define DH 64

typedef __bf16 v8bf __attribute__((ext_vector_type(8)));
typedef float f32x4 __attribute__((ext_vector_type(4)));
typedef unsigned short u16x4 __attribute__((ext_vector_type(4)));
typedef unsigned short u16x8 __attribute__((ext_vector_type(8)));

// Static device scratch (fully rewritten each launch)
__device__ __align__(16) unsigned short g_Xb[S_LEN * E_DIM];       // x as bf16 [s][e]
__device__ __align__(16) unsigned short g_WT[3 * E_DIM * E_DIM];   // [3072][1024] K-major Wq|Wk|Wv (bf16)
__device__ __align__(16) unsigned short g_WoT[E_DIM * E_DIM];      // [1024][1024] Wo^T (K-major, bf16)
__device__ __align__(16) unsigned short g_Qb[NH * S_LEN * DH];     // [h][s][d]
__device__ __align__(16) unsigned short g_Kb[NH * S_LEN * DH];     // [h][t][d]
__device__ __align__(16) unsigned short g_Vt[NH * DH * S_LEN];     // [h][d][t]  (V transposed)
__device__ __align__(16) unsigned short g_AO[S_LEN * E_DIM];       // [s][h*64+d] (bf16)

__device__ inline unsigned short f2bf(float f) {
    unsigned int u = __float_as_uint(f);
    u += 0x7FFF + ((u >> 16) & 1);   // RNE
    return (unsigned short)(u >> 16);
}
__device__ inline f32x4 mfma16(v8bf a, v8bf b, f32x4 c) {
    return __builtin_amdgcn_mfma_f32_16x16x32_bf16(a, b, c, 0, 0, 0);
}

// async global->LDS, 16B per lane; LDS dest = wave-uniform base + lane*16
typedef __attribute__((address_space(3))) unsigned int lds_u32;
typedef __attribute__((address_space(1))) const unsigned int glb_u32;
__device__ inline void async_cp16(const unsigned short* g, unsigned short* l) {
    __builtin_amdgcn_global_load_lds((glb_u32*)g, (lds_u32*)l, 16, 0, 0);
}

// ---------------- prep: convert x + transpose weights (vectorized) ----------------
__global__ __launch_bounds__(256) void prep(const float* __restrict__ X,
                                            const float* __restrict__ Wq,
                                            const float* __restrict__ Wk,
                                            const float* __restrict__ Wv,
                                            const float* __restrict__ Wo) {
    __shared__ __align__(16) unsigned short lds[64 * 72];
    const int b = blockIdx.x;
    const int t = threadIdx.x;
    if (b < 2048) {
        int i = b * 256 + t;
        f32x4 v = reinterpret_cast<const f32x4*>(X)[i];
        u16x4 o = {f2bf(v.x), f2bf(v.y), f2bf(v.z), f2bf(v.w)};
        reinterpret_cast<u16x4*>(g_Xb)[i] = o;
    } else if (b < 2304) {
        int bb = b - 2048;
        const int h = bb >> 4;
        const int e0 = (bb & 15) * 64;
        const float* srcs[3] = {Wq, Wk, Wv};
#pragma unroll
        for (int tn = 0; tn < 3; tn++) {
            const float* W = srcs[tn] + h * 65536;
#pragma unroll
            for (int p = 0; p < 4; p++) {
                int e = p * 16 + (t >> 4);
                int d = (t & 15) * 4;
                f32x4 v = *reinterpret_cast<const f32x4*>(&W[(e0 + e) * 64 + d]);
                lds[(d + 0) * 72 + e] = f2bf(v.x);
                lds[(d + 1) * 72 + e] = f2bf(v.y);
                lds[(d + 2) * 72 + e] = f2bf(v.z);
                lds[(d + 3) * 72 + e] = f2bf(v.w);
            }
            __syncthreads();
#pragma unroll
            for (int p = 0; p < 2; p++) {
                int d = p * 32 + (t >> 3);
                int ec = (t & 7) * 8;
                u16x8 o = *reinterpret_cast<const u16x8*>(&lds[d * 72 + ec]);
                *reinterpret_cast<u16x8*>(&g_WT[(tn * 1024 + h * 64 + d) * E_DIM + e0 + ec]) = o;
            }
            __syncthreads();
        }
    } else {
        int bb = b - 2304;
        const int f0 = (bb >> 4) * 64;
        const int e0 = (bb & 15) * 64;
#pragma unroll
        for (int p = 0; p < 4; p++) {
            int f = p * 16 + (t >> 4);
            int e = (t & 15) * 4;
            f32x4 v = *reinterpret_cast<const f32x4*>(&Wo[(f0 + f) * E_DIM + e0 + e]);
            lds[(e + 0) * 72 + f] = f2bf(v.x);
            lds[(e + 1) * 72 + f] = f2bf(v.y);
            lds[(e + 2) * 72 + f] = f2bf(v.z);
            lds[(e + 3) * 72 + f] = f2bf(v.w);
        }
        __syncthreads();
#pragma unroll
        for (int p = 0; p < 2; p++) {
            int e = p * 32 + (t >> 3);
            int fc = (t & 7) * 8;
            u16x8 o = *reinterpret_cast<const u16x8*>(&lds[e * 72 + fc]);
            *reinterpret_cast<u16x8*>(&g_WoT[(e0 + e) * E_DIM + f0 + fc]) = o;
        }
    }
}

// ---------------- QKV projection GEMM (128s x 64n, grid (16,48)) ----------------
__global__ __launch_bounds__(256) void qkv_gemm(const float* __restrict__ bq,
                                                const float* __restrict__ bk,
                                                const float* __restrict__ bv) {
    __shared__ __align__(16) unsigned short lds[12288];   // 24KB: lA 128x64, lB 64x64
    unsigned short* lA = lds;
    unsigned short* lB = lds + 8192;
    const int t = threadIdx.x;
    const int wave = t >> 6;
    const int lane = t & 63;
    const int m = lane & 15, quad = lane >> 4;
    const int s0 = blockIdx.x * 128;
    const int n0 = blockIdx.y * 64;

    const int rl = t >> 3;
    const int cx = (t & 7) ^ (rl & 7);
    const int axor = m & 7;

    f32x4 acc[2][4];
#pragma unroll
    for (int i = 0; i < 2; i++)
#pragma unroll
        for (int j = 0; j < 4; j++) acc[i][j] = (f32x4){0.f, 0.f, 0.f, 0.f};

    const unsigned short* lAr0 = lA + (wave * 32 + m) * 64;
    const unsigned short* lAr1 = lA + (wave * 32 + 16 + m) * 64;

    for (int k0 = 0; k0 < E_DIM; k0 += 64) {
        const unsigned short* ga = g_Xb + (s0 + rl) * E_DIM + k0 + cx * 8;
        async_cp16(ga,              lA + wave * 512);
        async_cp16(ga + 32 * E_DIM, lA + 2048 + wave * 512);
        async_cp16(ga + 64 * E_DIM, lA + 4096 + wave * 512);
        async_cp16(ga + 96 * E_DIM, lA + 6144 + wave * 512);
        const unsigned short* gb = g_WT + (n0 + rl) * E_DIM + k0 + cx * 8;
        async_cp16(gb,              lB + wave * 512);
        async_cp16(gb + 32 * E_DIM, lB + 2048 + wave * 512);
        __syncthreads();
#pragma unroll
        for (int ks = 0; ks < 2; ks++) {
            const int ch = ((ks * 4 + quad) ^ axor) * 8;
            v8bf a0 = *reinterpret_cast<const v8bf*>(lAr0 + ch);
            v8bf a1 = *reinterpret_cast<const v8bf*>(lAr1 + ch);
#pragma unroll
            for (int j = 0; j < 4; j++) {
                v8bf bfr = *reinterpret_cast<const v8bf*>(lB + (j * 16 + m) * 64 + ch);
                acc[0][j] = mfma16(a0, bfr, acc[0][j]);
                acc[1][j] = mfma16(a1, bfr, acc[1][j]);
            }
        }
        __syncthreads();
    }

    const int tensor = n0 >> 10;
    const int nn0 = n0 & 1023;
    const int hh = nn0 >> 6;
    const float* bb = tensor == 0 ? bq : (tensor == 1 ? bk : bv);
    float bias[4];
#pragma unroll
    for (int j = 0; j < 4; j++) bias[j] = bb[nn0 + j * 16 + m];

    if (tensor < 2) {
#pragma unroll
        for (int i = 0; i < 2; i++)
#pragma unroll
            for (int j = 0; j < 4; j++)
#pragma unroll
                for (int r = 0; r < 4; r++) {
                    int sl = wave * 32 + i * 16 + quad * 4 + r;
                    int nl = j * 16 + m;
                    lds[sl * 72 + nl] = f2bf(acc[i][j][r] + bias[j]);
                }
        __syncthreads();
        unsigned short* dst = (tensor == 0 ? g_Qb : g_Kb) + (hh * S_LEN + s0) * DH;
#pragma unroll
        for (int p = 0; p < 4; p++) {
            int row = p * 32 + (t >> 3);
            int c = t & 7;
            u16x8 v = *reinterpret_cast<const u16x8*>(&lds[row * 72 + c * 8]);
            *reinterpret_cast<u16x8*>(&dst[row * DH + c * 8]) = v;
        }
    } else {
#pragma unroll
        for (int i = 0; i < 2; i++)
#pragma unroll
            for (int j = 0; j < 4; j++)
#pragma unroll
                for (int r = 0; r < 4; r++) {
                    int sl = wave * 32 + i * 16 + quad * 4 + r;
                    int nl = j * 16 + m;
                    lds[nl * 136 + sl] = f2bf(acc[i][j][r] + bias[j]);
                }
        __syncthreads();
#pragma unroll
        for (int p = 0; p < 4; p++) {
            int nl = p * 16 + (t >> 4);
            int sc = t & 15;
            u16x8 v = *reinterpret_cast<const u16x8*>(&lds[nl * 136 + sc * 8]);
            *reinterpret_cast<u16x8*>(&g_Vt[(hh * DH + nl) * S_LEN + s0 + sc * 8]) = v;
        }
    }
}

// ---------------- causal flash attention ----------------
// Contiguous 32-row q-tile per block, 4-wave K-split (t0=wave*64, +=256).
// CU-balanced tile bijection {t,31-t,32+t,63-t}. l via ones-vector MFMA.
// K-frag prefetch: next iter's K loads issued during softmax/PV of current iter.
__global__ __launch_bounds__(256) void flash_attn() {
    __shared__ __align__(16) unsigned char smem[24576];
    unsigned short* plds = (unsigned short*)smem;        // per-wave 32x72 P region
    float* comb = (float*)smem;                          // [256][24] combine area
    const int t = threadIdx.x;
    const int wave = t >> 6, lane = t & 63;
    const int m = lane & 15, quad = lane >> 4;
    const int h = blockIdx.x & 15;
    const int Tp = blockIdx.x >> 4;                      // 0..63
    const int qq = Tp >> 4, tt = Tp & 15;
    const int T = (qq == 0) ? tt : (qq == 1) ? 31 - tt : (qq == 2) ? 32 + tt : 63 - tt;
    const int s0 = T * 32;

    const unsigned short* Qh = g_Qb + h * S_LEN * DH;
    const unsigned short* Kh = g_Kb + h * S_LEN * DH;
    const unsigned short* Vh = g_Vt + h * DH * S_LEN;

    v8bf aqA0 = *reinterpret_cast<const v8bf*>(Qh + (s0 + m) * DH + quad * 8);
    v8bf aqA1 = *reinterpret_cast<const v8bf*>(Qh + (s0 + m) * DH + 32 + quad * 8);
    v8bf aqB0 = *reinterpret_cast<const v8bf*>(Qh + (s0 + 16 + m) * DH + quad * 8);
    v8bf aqB1 = *reinterpret_cast<const v8bf*>(Qh + (s0 + 16 + m) * DH + 32 + quad * 8);

    f32x4 oA[4], oB[4];
#pragma unroll
    for (int i = 0; i < 4; i++) { oA[i] = (f32x4){0.f,0.f,0.f,0.f}; oB[i] = (f32x4){0.f,0.f,0.f,0.f}; }
    f32x4 laccA = (f32x4){0.f,0.f,0.f,0.f}, laccB = (f32x4){0.f,0.f,0.f,0.f};

    v8bf ones;
#pragma unroll
    for (int i = 0; i < 8; i++) ones[i] = (__bf16)1.0f;

    const float SC = 0.125f * 1.44269504088896f;         // 1/sqrt(64) * log2(e)
    unsigned short* pw = plds + wave * 2304;             // this wave's P region (32x72)
    const int tEnd = s0 + 32;

    int t0 = wave * 64;
    v8bf kf[4][2];
    if (t0 < tEnd) {
#pragma unroll
        for (int ct = 0; ct < 4; ct++) {
            const unsigned short* kp = Kh + (t0 + ct * 16 + m) * DH + quad * 8;
            kf[ct][0] = *reinterpret_cast<const v8bf*>(kp);
            kf[ct][1] = *reinterpret_cast<const v8bf*>(kp + 32);
        }
    }

    for (; t0 < tEnd; t0 += 256) {
        const bool doA = (t0 < s0 + 16);                 // wave-uniform
        const int t1 = t0 + 256;

        // V loads for this iter: issue early, latency hides behind QK + softmax
        v8bf vf[4][2];
#pragma unroll
        for (int dt = 0; dt < 4; dt++) {
            const unsigned short* vp = Vh + (dt * 16 + m) * S_LEN + t0 + quad * 8;
            vf[dt][0] = *reinterpret_cast<const v8bf*>(vp);
            vf[dt][1] = *reinterpret_cast<const v8bf*>(vp + 32);
        }

        f32x4 sB[4];
#pragma unroll
        for (int ct = 0; ct < 4; ct++) {
            sB[ct] = (f32x4){0.f,0.f,0.f,0.f};
            sB[ct] = mfma16(aqB0, kf[ct][0], sB[ct]);
            sB[ct] = mfma16(aqB1, kf[ct][1], sB[ct]);
        }
        f32x4 sA[4];
        if (doA) {
#pragma unroll
            for (int ct = 0; ct < 4; ct++) {
                sA[ct] = (f32x4){0.f,0.f,0.f,0.f};
                sA[ct] = mfma16(aqA0, kf[ct][0], sA[ct]);
                sA[ct] = mfma16(aqA1, kf[ct][1], sA[ct]);
            }
        }

        // prefetch next iter's K frags (latency hidden behind softmax + PV)
        v8bf kfn[4][2];
        if (t1 < tEnd) {
#pragma unroll
            for (int ct = 0; ct < 4; ct++) {
                const unsigned short* kp = Kh + (t1 + ct * 16 + m) * DH + quad * 8;
                kfn[ct][0] = *reinterpret_cast<const v8bf*>(kp);
                kfn[ct][1] = *reinterpret_cast<const v8bf*>(kp + 32);
            }
        }

        // causal masks (tile A rows s0.., tile B rows s0+16..)
#pragma unroll
        for (int ct = 0; ct < 4; ct++) {
            int colbase = t0 + ct * 16;
            int col = colbase + m;
            if (colbase + 15 > s0 + 16) {
#pragma unroll
                for (int r = 0; r < 4; r++)
                    if (col > s0 + 16 + quad * 4 + r) sB[ct][r] = -3e38f;
            }
            if (doA && colbase + 15 > s0) {
#pragma unroll
                for (int r = 0; r < 4; r++)
                    if (col > s0 + quad * 4 + r) sA[ct][r] = -3e38f;
            }
        }

        // p = exp2(s*SC); packed bf16 convert; P -> LDS (C-layout -> A-layout roundtrip)
#pragma unroll
        for (int ct = 0; ct < 4; ct++) {
#pragma unroll
            for (int r = 0; r < 4; r++)
                sB[ct][r] = __builtin_amdgcn_exp2f(sB[ct][r] * SC);
            __hip_bfloat162 p01 = __float22bfloat162_rn(make_float2(sB[ct][0], sB[ct][1]));
            __hip_bfloat162 p23 = __float22bfloat162_rn(make_float2(sB[ct][2], sB[ct][3]));
            unsigned short* pb = pw + (16 + quad * 4) * 72 + ct * 16 + m;
            pb[0]   = *reinterpret_cast<unsigned short*>(&p01.x);
            pb[72]  = *reinterpret_cast<unsigned short*>(&p01.y);
            pb[144] = *reinterpret_cast<unsigned short*>(&p23.x);
            pb[216] = *reinterpret_cast<unsigned short*>(&p23.y);
        }
        if (doA) {
#pragma unroll
            for (int ct = 0; ct < 4; ct++) {
#pragma unroll
                for (int r = 0; r < 4; r++)
                    sA[ct][r] = __builtin_amdgcn_exp2f(sA[ct][r] * SC);
                __hip_bfloat162 p01 = __float22bfloat162_rn(make_float2(sA[ct][0], sA[ct][1]));
                __hip_bfloat162 p23 = __float22bfloat162_rn(make_float2(sA[ct][2], sA[ct][3]));
                unsigned short* pa = pw + (quad * 4) * 72 + ct * 16 + m;
                pa[0]   = *reinterpret_cast<unsigned short*>(&p01.x);
                pa[72]  = *reinterpret_cast<unsigned short*>(&p01.y);
                pa[144] = *reinterpret_cast<unsigned short*>(&p23.x);
                pa[216] = *reinterpret_cast<unsigned short*>(&p23.y);
            }
        }
        __builtin_amdgcn_s_waitcnt(0xC07F);              // lgkmcnt(0): same-wave LDS roundtrip
        v8bf apB0 = *reinterpret_cast<const v8bf*>(pw + (16 + m) * 72 + quad * 8);
        v8bf apB1 = *reinterpret_cast<const v8bf*>(pw + (16 + m) * 72 + 32 + quad * 8);
#pragma unroll
        for (int dt = 0; dt < 4; dt++) {
            oB[dt] = mfma16(apB0, vf[dt][0], oB[dt]);
            oB[dt] = mfma16(apB1, vf[dt][1], oB[dt]);
        }
        laccB = mfma16(apB0, ones, laccB);               // l partial: rows match O's C-layout
        laccB = mfma16(apB1, ones, laccB);
        if (doA) {
            v8bf apA0 = *reinterpret_cast<const v8bf*>(pw + m * 72 + quad * 8);
            v8bf apA1 = *reinterpret_cast<const v8bf*>(pw + m * 72 + 32 + quad * 8);
#pragma unroll
            for (int dt = 0; dt < 4; dt++) {
                oA[dt] = mfma16(apA0, vf[dt][0], oA[dt]);
                oA[dt] = mfma16(apA1, vf[dt][1], oA[dt]);
            }
            laccA = mfma16(apA0, ones, laccA);
            laccA = mfma16(apA1, ones, laccA);
        }
        if (t1 < tEnd) {
#pragma unroll
            for (int ct = 0; ct < 4; ct++) {
                kf[ct][0] = kfn[ct][0];
                kf[ct][1] = kfn[ct][1];
            }
        }
    }

    // ---- 2-phase cross-wave combine (o,l additive; l already per-row) ----
    float* cw = comb + (wave * 64 + lane) * 24;
    __syncthreads();                                     // P regions dead
#pragma unroll
    for (int dt = 0; dt < 4; dt++) *reinterpret_cast<f32x4*>(cw + dt * 4) = oA[dt];
    *reinterpret_cast<f32x4*>(cw + 16) = laccA;
    __syncthreads();
    {
        f32x4 oAt = (f32x4){0.f,0.f,0.f,0.f}, l4 = (f32x4){0.f,0.f,0.f,0.f};
#pragma unroll
        for (int w = 0; w < 4; w++) {
            const float* cr = comb + (w * 64 + lane) * 24;
            oAt += *reinterpret_cast<const f32x4*>(cr + wave * 4);
            l4  += *reinterpret_cast<const f32x4*>(cr + 16);
        }
#pragma unroll
        for (int r = 0; r < 4; r++) {
            float inv = 1.0f / l4[r];
            g_AO[(s0 + quad * 4 + r) * E_DIM + h * 64 + wave * 16 + m] = f2bf(oAt[r] * inv);
        }
    }
    __syncthreads();
#pragma unroll
    for (int dt = 0; dt < 4; dt++) *reinterpret_cast<f32x4*>(cw + dt * 4) = oB[dt];
    *reinterpret_cast<f32x4*>(cw + 16) = laccB;
    __syncthreads();
    {
        f32x4 oBt = (f32x4){0.f,0.f,0.f,0.f}, l4 = (f32x4){0.f,0.f,0.f,0.f};
#pragma unroll
        for (int w = 0; w < 4; w++) {
            const float* cr = comb + (w * 64 + lane) * 24;
            oBt += *reinterpret_cast<const f32x4*>(cr + wave * 4);
            l4  += *reinterpret_cast<const f32x4*>(cr + 16);
        }
#pragma unroll
        for (int r = 0; r < 4; r++) {
            float inv = 1.0f / l4[r];
            g_AO[(s0 + 16 + quad * 4 + r) * E_DIM + h * 64 + wave * 16 + m] = f2bf(oBt[r] * inv);
        }
    }
}

// ---------------- output projection (64s x 64n, grid (32,16)) ----------------
__global__ __launch_bounds__(256) void out_gemm(const float* __restrict__ bo,
                                                float* __restrict__ OUT) {
    __shared__ __align__(16) unsigned short lds[8192];
    unsigned short* lA = lds;
    unsigned short* lB = lds + 4096;
    const int t = threadIdx.x;
    const int wave = t >> 6;
    const int lane = t & 63;
    const int m = lane & 15, quad = lane >> 4;
    const int wr = (wave >> 1) * 32, wc = (wave & 1) * 32;
    const int s0 = blockIdx.x * 64;
    const int n0 = blockIdx.y * 64;

    const int rl = t >> 3;
    const int cx = (t & 7) ^ (rl & 7);
    const int axor = m & 7;

    f32x4 acc[2][2];
#pragma unroll
    for (int i = 0; i < 2; i++)
#pragma unroll
        for (int j = 0; j < 2; j++) acc[i][j] = (f32x4){0.f, 0.f, 0.f, 0.f};

    for (int k0 = 0; k0 < E_DIM; k0 += 64) {
        const unsigned short* ga = g_AO + (s0 + rl) * E_DIM + k0 + cx * 8;
        async_cp16(ga,              lA + wave * 512);
        async_cp16(ga + 32 * E_DIM, lA + 2048 + wave * 512);
        const unsigned short* gb = g_WoT + (n0 + rl) * E_DIM + k0 + cx * 8;
        async_cp16(gb,              lB + wave * 512);
        async_cp16(gb + 32 * E_DIM, lB + 2048 + wave * 512);
        __syncthreads();
#pragma unroll
        for (int ks = 0; ks < 2; ks++) {
            const int ch = ((ks * 4 + quad) ^ axor) * 8;
            v8bf a0 = *reinterpret_cast<const v8bf*>(lA + (wr + m) * 64 + ch);
            v8bf a1 = *reinterpret_cast<const v8bf*>(lA + (wr + 16 + m) * 64 + ch);
#pragma unroll
            for (int j = 0; j < 2; j++) {
                v8bf bfr = *reinterpret_cast<const v8bf*>(lB + (wc + j * 16 + m) * 64 + ch);
                acc[0][j] = mfma16(a0, bfr, acc[0][j]);
                acc[1][j] = mfma16(a1, bfr, acc[1][j]);
            }
        }
        __syncthreads();
    }
#pragma unroll
    for (int i = 0; i < 2; i++)
#pragma unroll
        for (int j = 0; j < 2; j++) {
            int e = n0 + wc + j * 16 + m;
            float bias = bo[e];
#pragma unroll
            for (int r = 0; r < 4; r++) {
                int s = s0 + wr + i * 16 + quad * 4 + r;
                OUT[s * E_DIM + e] = acc[i][j][r] + bias;
            }
        }
}

extern "C" void kernel_launch(void* const* d_in, const int* in_sizes, int n_in,
                              void* d_out, int out_size, void* d_ws, size_t ws_size,
                              hipStream_t stream) {
    (void)in_sizes; (void)n_in; (void)out_size; (void)d_ws; (void)ws_size;
    const float* x  = (const float*)d_in[0];
    const float* Wq = (const float*)d_in[1];
    const float* bq = (const float*)d_in[2];
    const float* Wk = (const float*)d_in[3];
    const float* bk = (const float*)d_in[4];
    const float* Wv = (const float*)d_in[5];
    const float* bv = (const float*)d_in[6];
    const float* Wo = (const float*)d_in[7];
    const float* bo = (const float*)d_in[8];
    float* out = (float*)d_out;

    hipLaunchKernelGGL(prep,       dim3(2560),   dim3(256), 0, stream, x, Wq, Wk, Wv, Wo);
    hipLaunchKernelGGL(qkv_gemm,   dim3(16, 48), dim3(256), 0, stream, bq, bk, bv);
    hipLaunchKernelGGL(flash_attn, dim3(1024),   dim3(256), 0, stream);
    hipLaunchKernelGGL(out_gemm,   dim3(32, 16), dim3(256), 0, stream, bo, out);
}